// Round 14
// baseline (74.984 us; speedup 1.0000x reference)
//
#include <hip/hip_runtime.h>

typedef unsigned short US;
typedef __bf16 bf16x8 __attribute__((ext_vector_type(8)));
typedef float f32x4 __attribute__((ext_vector_type(4)));

__device__ __forceinline__ US f2bf(float f) {
  union { float f; unsigned u; } v; v.f = f;
  unsigned r = v.u + 0x7fffu + ((v.u >> 16) & 1u);
  return (US)(r >> 16);
}
__device__ __forceinline__ float blo(unsigned u) {
  union { unsigned u; float f; } v; v.u = u << 16; return v.f;
}
__device__ __forceinline__ float bhi(unsigned u) {
  union { unsigned u; float f; } v; v.u = u & 0xffff0000u; return v.f;
}

// ---------------- kernel 0: pw_w fp32 -> bf16 ----------------
__global__ __launch_bounds__(256) void k_convw(const float* __restrict__ pw,
                                               US* __restrict__ wb) {
  int i = (blockIdx.x * 256 + threadIdx.x) * 4;
  float4 v = *(const float4*)(pw + i);
  ushort4 s;
  s.x = f2bf(v.x); s.y = f2bf(v.y); s.z = f2bf(v.z); s.w = f2bf(v.w);
  *(ushort4*)(wb + i) = s;
}

// ---------------- kernel 1: depthwise 7x7 -> y8 [b][c/8][px][8c] ----------------
// bf16 LDS staging (40KB total) + __launch_bounds__(512,4) => 4 blocks/CU,
// 32 waves/CU. Measured ~27us warm / ~33us cold (R12/R13 joint fit).
__global__ __launch_bounds__(512, 4) void k_dw(const float* __restrict__ x,
                                               const float* __restrict__ dww,
                                               const float* __restrict__ dwb,
                                               US* __restrict__ y8) {
  const int bid = blockIdx.x;           // b(16) * cg(32) * rg(4)
  const int rg  = bid & 3;
  const int cg  = (bid >> 2) & 31;
  const int b   = bid >> 7;
  const int t   = threadIdx.x;
  const int w   = t >> 6;               // wave id = channel slot 0..7
  const int l   = t & 63;
  const int g   = l >> 4;               // row quad 0..3
  const int cb  = l & 15;               // col quad 0..15
  const int c   = __builtin_amdgcn_readfirstlane(cg * 8 + w);  // wave-uniform
  const float* xp = x + ((size_t)b * 256 + c) * 4096;

  __shared__ US xl[8][24][64];          // 24 KB: staged input rows (bf16)
  __shared__ US t8[8][1024];            // 16 KB: pack transpose tile

  const int r0 = rg * 16;

  // ---- stage: rows r0-3 .. r0+20 (clamped), fp32 -> bf16, 3 b128 writes ----
  {
    const int rowl0 = l >> 3;           // 0..7
    const int colb  = (l & 7) * 8;      // bf16 col base (16B chunk)
#pragma unroll
    for (int it = 0; it < 3; ++it) {
      const int rowl = it * 8 + rowl0;
      const int gr   = r0 - 3 + rowl;
      const int grc  = min(max(gr, 0), 63);     // clamped: always valid
      const float* gp = xp + grc * 64 + colb;
      float4 f0 = *(const float4*)(gp);
      float4 f1 = *(const float4*)(gp + 4);
      uint4 pk;
      pk.x = ((unsigned)f2bf(f0.y) << 16) | f2bf(f0.x);
      pk.y = ((unsigned)f2bf(f0.w) << 16) | f2bf(f0.z);
      pk.z = ((unsigned)f2bf(f1.y) << 16) | f2bf(f1.x);
      pk.w = ((unsigned)f2bf(f1.w) << 16) | f2bf(f1.z);
      *(uint4*)&xl[w][rowl][colb] = pk;
    }
  }

  float wv[49];
  const float* wp = dww + c * 49;       // wave-uniform -> s_load -> SGPRs
#pragma unroll
  for (int i = 0; i < 49; ++i) wv[i] = wp[i];
  const float bias = dwb[c];

  __syncthreads();

  // ---- compute: 4x4 thread tile, reads bf16 LDS only ----
  const int bcx  = cb * 4;
  const bool colL = (bcx >= 4);
  const bool colR = (bcx < 60);
  const int offL  = colL ? -4 : 0;      // US units; cndmask'd, stays in-bounds
  const int offR  = colR ?  4 : 0;

  float acc[4][4];
#pragma unroll
  for (int o = 0; o < 4; ++o)
#pragma unroll
    for (int q = 0; q < 4; ++q) acc[o][q] = bias;

#pragma unroll
  for (int j = 0; j < 10; ++j) {
    const int gr = r0 + g * 4 - 3 + j;        // global input row
    const bool rowOK = ((unsigned)gr < 64u);
    const US* rp = &xl[w][g * 4 + j][bcx];    // local row 0..21, in-bounds
    uint2 va = *(const uint2*)(rp + offL);
    uint2 vb = *(const uint2*)(rp);
    uint2 vc = *(const uint2*)(rp + offR);
    const bool okL = rowOK && colL;
    const bool okR = rowOK && colR;
    va.x = okL   ? va.x : 0u;  va.y = okL   ? va.y : 0u;
    vb.x = rowOK ? vb.x : 0u;  vb.y = rowOK ? vb.y : 0u;
    vc.x = okR   ? vc.x : 0u;  vc.y = okR   ? vc.y : 0u;
    float L[12];
    L[0] = blo(va.x); L[1]  = bhi(va.x); L[2]  = blo(va.y); L[3]  = bhi(va.y);
    L[4] = blo(vb.x); L[5]  = bhi(vb.x); L[6]  = blo(vb.y); L[7]  = bhi(vb.y);
    L[8] = blo(vc.x); L[9]  = bhi(vc.x); L[10] = blo(vc.y); L[11] = bhi(vc.y);
#pragma unroll
    for (int o = 0; o < 4; ++o) {
      if (j - o >= 0 && j - o <= 6) {   // compile-time after unroll
        const int kh = j - o;
#pragma unroll
        for (int kw = 0; kw < 7; ++kw) {
          const float wk = wv[kh * 7 + kw];
#pragma unroll
          for (int q = 0; q < 4; ++q)
            acc[o][q] = fmaf(L[q + kw + 1], wk, acc[o][q]);
        }
      }
    }
  }

  // LDS transpose: [8c][1024 px], then pack px-pairs into y8 uint4s
#pragma unroll
  for (int o = 0; o < 4; ++o) {
    ushort4 s;
    s.x = f2bf(acc[o][0]); s.y = f2bf(acc[o][1]);
    s.z = f2bf(acc[o][2]); s.w = f2bf(acc[o][3]);
    *(ushort4*)&t8[w][(g * 4 + o) * 64 + bcx] = s;
  }
  __syncthreads();

  unsigned rc8[8];
#pragma unroll
  for (int c2 = 0; c2 < 8; ++c2) rc8[c2] = *(const unsigned*)&t8[c2][2 * t];
  uint4 A, B2;
  A.x  = __builtin_amdgcn_perm(rc8[1], rc8[0], 0x05040100u);  // px even: c0..c7
  A.y  = __builtin_amdgcn_perm(rc8[3], rc8[2], 0x05040100u);
  A.z  = __builtin_amdgcn_perm(rc8[5], rc8[4], 0x05040100u);
  A.w  = __builtin_amdgcn_perm(rc8[7], rc8[6], 0x05040100u);
  B2.x = __builtin_amdgcn_perm(rc8[1], rc8[0], 0x07060302u);  // px odd
  B2.y = __builtin_amdgcn_perm(rc8[3], rc8[2], 0x07060302u);
  B2.z = __builtin_amdgcn_perm(rc8[5], rc8[4], 0x07060302u);
  B2.w = __builtin_amdgcn_perm(rc8[7], rc8[6], 0x07060302u);
  US* yb = y8 + (((size_t)b * 32 + cg) * 4096 + r0 * 64) * 8 + (size_t)t * 16;
  *(uint4*)(yb)     = A;
  *(uint4*)(yb + 8) = B2;
}

// ---------------- kernel 2: pointwise GEMM (MFMA bf16) ----------------
// out^T fragments via swapped operands; double-buffered LDS; XCD swizzle.
// A-operand from PRECONVERTED bf16 wb (R13's fp32-fused variant cost ~20us:
// fp32 loads + f2bf chain held ~32 extra VGPRs live across the MFMA block).
__global__ __launch_bounds__(256, 2) void k_pw(const US* __restrict__ y8,
                                               const US* __restrict__ wb,
                                               const float* __restrict__ pwb,
                                               float* __restrict__ out) {
  // bijective XCD swizzle (nwg=2048, %8==0): chunk of 256 per XCD
  const int bid = blockIdx.x;
  const int s   = ((bid & 7) << 8) | (bid >> 3);
  const int b   = s >> 7;
  const int rr  = s & 127;
  const int nt  = rr >> 2;        // px tile (32)
  const int mt  = rr & 3;         // o tile (4) innermost -> y8-tile L2 reuse
  const int o0  = mt * 128;
  const int hw0 = nt * 128;

  __shared__ US lsA[2][128][72];
  __shared__ US lsB[2][128][72];
  const int tid  = threadIdx.x;
  const int lane = tid & 63;
  const int wid  = tid >> 6;
  const int wm   = wid >> 1, wn = wid & 1;
  const int strow = tid >> 3;     // A-stage: 0..31
  const int scg   = tid & 7;      // A-stage: 16B chunk within 128B k-row
  const int bg    = tid >> 5;     // B-stage: 8c-group 0..7
  const int bl    = tid & 31;     // B-stage: px within group of 32

  const f32x4 fzero = {0.f, 0.f, 0.f, 0.f};
  f32x4 acc[4][4];
#pragma unroll
  for (int m = 0; m < 4; ++m)
#pragma unroll
    for (int n = 0; n < 4; ++n) acc[m][n] = fzero;

  uint4 ra[4], rb[4];
  // prologue: stage kt=0 into buffer 0
#pragma unroll
  for (int i = 0; i < 4; ++i) {
    ra[i] = *(const uint4*)(wb + (size_t)(o0 + i * 32 + strow) * 256 + scg * 8);
    rb[i] = *(const uint4*)(y8 + ((size_t)(b * 32 + bg) * 4096 + hw0 + bl + 32 * i) * 8);
  }
#pragma unroll
  for (int i = 0; i < 4; ++i) {
    *(uint4*)&lsA[0][i * 32 + strow][scg * 8] = ra[i];
    *(uint4*)&lsB[0][bl + 32 * i][bg * 8]     = rb[i];
  }
  __syncthreads();

  for (int kt = 0; kt < 4; ++kt) {
    const int cur = kt & 1;
    // issue-early: global loads for next tile (hide under compute)
    if (kt < 3) {
      const int ck = (kt + 1) * 64;
#pragma unroll
      for (int i = 0; i < 4; ++i) {
        ra[i] = *(const uint4*)(wb + (size_t)(o0 + i * 32 + strow) * 256 + ck + scg * 8);
        rb[i] = *(const uint4*)(y8 + ((size_t)(b * 32 + (ck >> 3) + bg) * 4096 + hw0 + bl + 32 * i) * 8);
      }
    }
    bf16x8 af[2][4], bfr[2][4];
#pragma unroll
    for (int kk = 0; kk < 2; ++kk) {
      const int kcol = kk * 32 + (lane >> 4) * 8;
#pragma unroll
      for (int m = 0; m < 4; ++m)
        af[kk][m] = *reinterpret_cast<const bf16x8*>(&lsA[cur][wm * 64 + m * 16 + (lane & 15)][kcol]);
#pragma unroll
      for (int n = 0; n < 4; ++n)
        bfr[kk][n] = *reinterpret_cast<const bf16x8*>(&lsB[cur][wn * 64 + n * 16 + (lane & 15)][kcol]);
    }
#pragma unroll
    for (int kk = 0; kk < 2; ++kk)
#pragma unroll
      for (int m = 0; m < 4; ++m)
#pragma unroll
        for (int n = 0; n < 4; ++n)
          // swapped operands: acc = (Y^T)*(W^T) = out^T fragment
          acc[m][n] = __builtin_amdgcn_mfma_f32_16x16x32_bf16(bfr[kk][n], af[kk][m], acc[m][n], 0, 0, 0);

    if (kt < 3) {
#pragma unroll
      for (int i = 0; i < 4; ++i) {
        *(uint4*)&lsA[cur ^ 1][i * 32 + strow][scg * 8] = ra[i];
        *(uint4*)&lsB[cur ^ 1][bl + 32 * i][bg * 8]     = rb[i];
      }
      __syncthreads();
    }
  }

  // epilogue: D^T layout -> lane holds 4 consecutive px at fixed o: dwordx4 stores
#pragma unroll
  for (int m = 0; m < 4; ++m) {
    const int o  = o0 + wm * 64 + m * 16 + (lane & 15);
    const float bv = pwb[o];
    float* orow = out + (((size_t)b * 512 + o) * 4096) + hw0 + wn * 64 + (lane >> 4) * 4;
#pragma unroll
    for (int n = 0; n < 4; ++n) {
      f32x4 v = acc[m][n];
      v[0] += bv; v[1] += bv; v[2] += bv; v[3] += bv;
      *(f32x4*)(orow + n * 16) = v;
    }
  }
}

extern "C" void kernel_launch(void* const* d_in, const int* in_sizes, int n_in,
                              void* d_out, int out_size, void* d_ws, size_t ws_size,
                              hipStream_t stream) {
  const float* x   = (const float*)d_in[0];
  const float* dww = (const float*)d_in[1];
  const float* dwb = (const float*)d_in[2];
  const float* pww = (const float*)d_in[3];
  const float* pwb = (const float*)d_in[4];
  float* out = (float*)d_out;

  char* ws = (char*)d_ws;
  US* y8  = (US*)ws;                         // 16*32*4096*8 bf16 = 33,554,432 B
  US* wbf = (US*)(ws + 33554432);            // 512*256 bf16 = 262,144 B

  k_convw<<<128,  256, 0, stream>>>(pww, wbf);
  k_dw   <<<2048, 512, 0, stream>>>(x, dww, dwb, y8);
  k_pw   <<<2048, 256, 0, stream>>>(y8, wbf, pwb, out);
}

// Round 15
// 72.725 us; speedup vs baseline: 1.0311x; 1.0311x over previous
//
#include <hip/hip_runtime.h>

typedef unsigned short US;
typedef __bf16 bf16x8 __attribute__((ext_vector_type(8)));
typedef float f32x4 __attribute__((ext_vector_type(4)));

__device__ __forceinline__ US f2bf(float f) {
  union { float f; unsigned u; } v; v.f = f;
  unsigned r = v.u + 0x7fffu + ((v.u >> 16) & 1u);
  return (US)(r >> 16);
}
__device__ __forceinline__ float blo(unsigned u) {
  union { unsigned u; float f; } v; v.u = u << 16; return v.f;
}
__device__ __forceinline__ float bhi(unsigned u) {
  union { unsigned u; float f; } v; v.u = u & 0xffff0000u; return v.f;
}

// ---------------- kernel 0: pw_w fp32 -> bf16 ----------------
__global__ __launch_bounds__(256) void k_convw(const float* __restrict__ pw,
                                               US* __restrict__ wb) {
  int i = (blockIdx.x * 256 + threadIdx.x) * 4;
  float4 v = *(const float4*)(pw + i);
  ushort4 s;
  s.x = f2bf(v.x); s.y = f2bf(v.y); s.z = f2bf(v.z); s.w = f2bf(v.w);
  *(ushort4*)(wb + i) = s;
}

// ---------------- kernel 1: depthwise 7x7 -> y8 [b][c/8][px][8c] ----------------
// bf16 LDS staging + (512,4). NEW (R15): the stage->compute sync is WAVE-LOCAL
// (wave w writes/reads only xl[w]) — s_waitcnt + wave_barrier instead of
// __syncthreads. Kills the block-wide convoy: each wave starts FMAs as soon
// as ITS loads land; waves de-phase and cover each other's HBM latency.
__global__ __launch_bounds__(512, 4) void k_dw(const float* __restrict__ x,
                                               const float* __restrict__ dww,
                                               const float* __restrict__ dwb,
                                               US* __restrict__ y8) {
  const int bid = blockIdx.x;           // b(16) * cg(32) * rg(4)
  const int rg  = bid & 3;
  const int cg  = (bid >> 2) & 31;
  const int b   = bid >> 7;
  const int t   = threadIdx.x;
  const int w   = t >> 6;               // wave id = channel slot 0..7
  const int l   = t & 63;
  const int g   = l >> 4;               // row quad 0..3
  const int cb  = l & 15;               // col quad 0..15
  const int c   = __builtin_amdgcn_readfirstlane(cg * 8 + w);  // wave-uniform
  const float* xp = x + ((size_t)b * 256 + c) * 4096;

  __shared__ US xl[8][24][64];          // 24 KB: staged input rows (bf16)
  __shared__ US t8[8][1024];            // 16 KB: pack transpose tile

  const int r0 = rg * 16;

  // ---- stage: rows r0-3 .. r0+20 (clamped), fp32 -> bf16, 3 b128 writes ----
  {
    const int rowl0 = l >> 3;           // 0..7
    const int colb  = (l & 7) * 8;      // bf16 col base (16B chunk)
#pragma unroll
    for (int it = 0; it < 3; ++it) {
      const int rowl = it * 8 + rowl0;
      const int gr   = r0 - 3 + rowl;
      const int grc  = min(max(gr, 0), 63);     // clamped: always valid
      const float* gp = xp + grc * 64 + colb;
      float4 f0 = *(const float4*)(gp);
      float4 f1 = *(const float4*)(gp + 4);
      uint4 pk;
      pk.x = ((unsigned)f2bf(f0.y) << 16) | f2bf(f0.x);
      pk.y = ((unsigned)f2bf(f0.w) << 16) | f2bf(f0.z);
      pk.z = ((unsigned)f2bf(f1.y) << 16) | f2bf(f1.x);
      pk.w = ((unsigned)f2bf(f1.w) << 16) | f2bf(f1.z);
      *(uint4*)&xl[w][rowl][colb] = pk;
    }
  }

  float wv[49];
  const float* wp = dww + c * 49;       // wave-uniform -> s_load -> SGPRs
#pragma unroll
  for (int i = 0; i < 49; ++i) wv[i] = wp[i];
  const float bias = dwb[c];

  // WAVE-LOCAL sync: xl[w] is written and read only by wave w.
  asm volatile("s_waitcnt vmcnt(0) lgkmcnt(0)" ::: "memory");
  __builtin_amdgcn_wave_barrier();

  // ---- compute: 4x4 thread tile, reads bf16 LDS only ----
  const int bcx  = cb * 4;
  const bool colL = (bcx >= 4);
  const bool colR = (bcx < 60);
  const int offL  = colL ? -4 : 0;      // US units; cndmask'd, stays in-bounds
  const int offR  = colR ?  4 : 0;

  float acc[4][4];
#pragma unroll
  for (int o = 0; o < 4; ++o)
#pragma unroll
    for (int q = 0; q < 4; ++q) acc[o][q] = bias;

#pragma unroll
  for (int j = 0; j < 10; ++j) {
    const int gr = r0 + g * 4 - 3 + j;        // global input row
    const bool rowOK = ((unsigned)gr < 64u);
    const US* rp = &xl[w][g * 4 + j][bcx];    // local row 0..21, in-bounds
    uint2 va = *(const uint2*)(rp + offL);
    uint2 vb = *(const uint2*)(rp);
    uint2 vc = *(const uint2*)(rp + offR);
    const bool okL = rowOK && colL;
    const bool okR = rowOK && colR;
    va.x = okL   ? va.x : 0u;  va.y = okL   ? va.y : 0u;
    vb.x = rowOK ? vb.x : 0u;  vb.y = rowOK ? vb.y : 0u;
    vc.x = okR   ? vc.x : 0u;  vc.y = okR   ? vc.y : 0u;
    float L[12];
    L[0] = blo(va.x); L[1]  = bhi(va.x); L[2]  = blo(va.y); L[3]  = bhi(va.y);
    L[4] = blo(vb.x); L[5]  = bhi(vb.x); L[6]  = blo(vb.y); L[7]  = bhi(vb.y);
    L[8] = blo(vc.x); L[9]  = bhi(vc.x); L[10] = blo(vc.y); L[11] = bhi(vc.y);
#pragma unroll
    for (int o = 0; o < 4; ++o) {
      if (j - o >= 0 && j - o <= 6) {   // compile-time after unroll
        const int kh = j - o;
#pragma unroll
        for (int kw = 0; kw < 7; ++kw) {
          const float wk = wv[kh * 7 + kw];
#pragma unroll
          for (int q = 0; q < 4; ++q)
            acc[o][q] = fmaf(L[q + kw + 1], wk, acc[o][q]);
        }
      }
    }
  }

  // LDS transpose: [8c][1024 px], then pack px-pairs into y8 uint4s
#pragma unroll
  for (int o = 0; o < 4; ++o) {
    ushort4 s;
    s.x = f2bf(acc[o][0]); s.y = f2bf(acc[o][1]);
    s.z = f2bf(acc[o][2]); s.w = f2bf(acc[o][3]);
    *(ushort4*)&t8[w][(g * 4 + o) * 64 + bcx] = s;
  }
  __syncthreads();                      // cross-wave: pack reads all 8 channels

  unsigned rc8[8];
#pragma unroll
  for (int c2 = 0; c2 < 8; ++c2) rc8[c2] = *(const unsigned*)&t8[c2][2 * t];
  uint4 A, B2;
  A.x  = __builtin_amdgcn_perm(rc8[1], rc8[0], 0x05040100u);  // px even: c0..c7
  A.y  = __builtin_amdgcn_perm(rc8[3], rc8[2], 0x05040100u);
  A.z  = __builtin_amdgcn_perm(rc8[5], rc8[4], 0x05040100u);
  A.w  = __builtin_amdgcn_perm(rc8[7], rc8[6], 0x05040100u);
  B2.x = __builtin_amdgcn_perm(rc8[1], rc8[0], 0x07060302u);  // px odd
  B2.y = __builtin_amdgcn_perm(rc8[3], rc8[2], 0x07060302u);
  B2.z = __builtin_amdgcn_perm(rc8[5], rc8[4], 0x07060302u);
  B2.w = __builtin_amdgcn_perm(rc8[7], rc8[6], 0x07060302u);
  US* yb = y8 + (((size_t)b * 32 + cg) * 4096 + r0 * 64) * 8 + (size_t)t * 16;
  *(uint4*)(yb)     = A;
  *(uint4*)(yb + 8) = B2;
}

// ---------------- kernel 2: pointwise GEMM (MFMA bf16) ----------------
// out^T fragments via swapped operands; double-buffered LDS; XCD swizzle.
__global__ __launch_bounds__(256, 2) void k_pw(const US* __restrict__ y8,
                                               const US* __restrict__ wb,
                                               const float* __restrict__ pwb,
                                               float* __restrict__ out) {
  // bijective XCD swizzle (nwg=2048, %8==0): chunk of 256 per XCD
  const int bid = blockIdx.x;
  const int s   = ((bid & 7) << 8) | (bid >> 3);
  const int b   = s >> 7;
  const int rr  = s & 127;
  const int nt  = rr >> 2;        // px tile (32)
  const int mt  = rr & 3;         // o tile (4) innermost -> y8-tile L2 reuse
  const int o0  = mt * 128;
  const int hw0 = nt * 128;

  __shared__ US lsA[2][128][72];
  __shared__ US lsB[2][128][72];
  const int tid  = threadIdx.x;
  const int lane = tid & 63;
  const int wid  = tid >> 6;
  const int wm   = wid >> 1, wn = wid & 1;
  const int strow = tid >> 3;     // A-stage: 0..31
  const int scg   = tid & 7;      // A-stage: 16B chunk within 128B k-row
  const int bg    = tid >> 5;     // B-stage: 8c-group 0..7
  const int bl    = tid & 31;     // B-stage: px within group of 32

  const f32x4 fzero = {0.f, 0.f, 0.f, 0.f};
  f32x4 acc[4][4];
#pragma unroll
  for (int m = 0; m < 4; ++m)
#pragma unroll
    for (int n = 0; n < 4; ++n) acc[m][n] = fzero;

  uint4 ra[4], rb[4];
  // prologue: stage kt=0 into buffer 0
#pragma unroll
  for (int i = 0; i < 4; ++i) {
    ra[i] = *(const uint4*)(wb + (size_t)(o0 + i * 32 + strow) * 256 + scg * 8);
    rb[i] = *(const uint4*)(y8 + ((size_t)(b * 32 + bg) * 4096 + hw0 + bl + 32 * i) * 8);
  }
#pragma unroll
  for (int i = 0; i < 4; ++i) {
    *(uint4*)&lsA[0][i * 32 + strow][scg * 8] = ra[i];
    *(uint4*)&lsB[0][bl + 32 * i][bg * 8]     = rb[i];
  }
  __syncthreads();

  for (int kt = 0; kt < 4; ++kt) {
    const int cur = kt & 1;
    // issue-early: global loads for next tile (hide under compute)
    if (kt < 3) {
      const int ck = (kt + 1) * 64;
#pragma unroll
      for (int i = 0; i < 4; ++i) {
        ra[i] = *(const uint4*)(wb + (size_t)(o0 + i * 32 + strow) * 256 + ck + scg * 8);
        rb[i] = *(const uint4*)(y8 + ((size_t)(b * 32 + (ck >> 3) + bg) * 4096 + hw0 + bl + 32 * i) * 8);
      }
    }
    bf16x8 af[2][4], bfr[2][4];
#pragma unroll
    for (int kk = 0; kk < 2; ++kk) {
      const int kcol = kk * 32 + (lane >> 4) * 8;
#pragma unroll
      for (int m = 0; m < 4; ++m)
        af[kk][m] = *reinterpret_cast<const bf16x8*>(&lsA[cur][wm * 64 + m * 16 + (lane & 15)][kcol]);
#pragma unroll
      for (int n = 0; n < 4; ++n)
        bfr[kk][n] = *reinterpret_cast<const bf16x8*>(&lsB[cur][wn * 64 + n * 16 + (lane & 15)][kcol]);
    }
#pragma unroll
    for (int kk = 0; kk < 2; ++kk)
#pragma unroll
      for (int m = 0; m < 4; ++m)
#pragma unroll
        for (int n = 0; n < 4; ++n)
          // swapped operands: acc = (Y^T)*(W^T) = out^T fragment
          acc[m][n] = __builtin_amdgcn_mfma_f32_16x16x32_bf16(bfr[kk][n], af[kk][m], acc[m][n], 0, 0, 0);

    if (kt < 3) {
#pragma unroll
      for (int i = 0; i < 4; ++i) {
        *(uint4*)&lsA[cur ^ 1][i * 32 + strow][scg * 8] = ra[i];
        *(uint4*)&lsB[cur ^ 1][bl + 32 * i][bg * 8]     = rb[i];
      }
      __syncthreads();
    }
  }

  // epilogue: D^T layout -> lane holds 4 consecutive px at fixed o: dwordx4 stores
#pragma unroll
  for (int m = 0; m < 4; ++m) {
    const int o  = o0 + wm * 64 + m * 16 + (lane & 15);
    const float bv = pwb[o];
    float* orow = out + (((size_t)b * 512 + o) * 4096) + hw0 + wn * 64 + (lane >> 4) * 4;
#pragma unroll
    for (int n = 0; n < 4; ++n) {
      f32x4 v = acc[m][n];
      v[0] += bv; v[1] += bv; v[2] += bv; v[3] += bv;
      *(f32x4*)(orow + n * 16) = v;
    }
  }
}

extern "C" void kernel_launch(void* const* d_in, const int* in_sizes, int n_in,
                              void* d_out, int out_size, void* d_ws, size_t ws_size,
                              hipStream_t stream) {
  const float* x   = (const float*)d_in[0];
  const float* dww = (const float*)d_in[1];
  const float* dwb = (const float*)d_in[2];
  const float* pww = (const float*)d_in[3];
  const float* pwb = (const float*)d_in[4];
  float* out = (float*)d_out;

  char* ws = (char*)d_ws;
  US* y8  = (US*)ws;                         // 16*32*4096*8 bf16 = 33,554,432 B
  US* wbf = (US*)(ws + 33554432);            // 512*256 bf16 = 262,144 B

  k_convw<<<128,  256, 0, stream>>>(pww, wbf);
  k_dw   <<<2048, 512, 0, stream>>>(x, dww, dwb, y8);
  k_pw   <<<2048, 256, 0, stream>>>(y8, wbf, pwb, out);
}